// Round 1
// baseline (495.658 us; speedup 1.0000x reference)
//
#include <hip/hip_runtime.h>
#include <hip/hip_bf16.h>
#include <cstdint>
#include <cstddef>

// ---- constants (fixed by the reference problem) ----
#define Hh 1024
#define D_EMB 512
#define D_UP 2048
#define BT 16384      // B*T
#define BB_ 512
#define Mm 4096
#define NB 32         // BT/BB

typedef __attribute__((ext_vector_type(4))) float f4;
typedef __attribute__((ext_vector_type(4))) __bf16 bf4;
typedef __attribute__((ext_vector_type(8))) __bf16 bf8;
typedef __attribute__((ext_vector_type(4))) float f32x4;

// ---------------- helpers ----------------
__device__ __forceinline__ void gl_lds16(const void* g, void* l) {
  __builtin_amdgcn_global_load_lds((__attribute__((address_space(1))) void*)g,
                                   (__attribute__((address_space(3))) void*)l, 16, 0, 0);
}

// ---------------- prep kernels ----------------
__global__ __launch_bounds__(256) void conv_bf16_kernel(const float* __restrict__ src,
                                                        __bf16* __restrict__ dst, int n4) {
  int i = blockIdx.x * 256 + threadIdx.x;
  if (i >= n4) return;
  f4 v = ((const f4*)src)[i];
  bf4 o = {(__bf16)v[0], (__bf16)v[1], (__bf16)v[2], (__bf16)v[3]};
  ((bf4*)dst)[i] = o;
}

__global__ __launch_bounds__(256) void gather_bf16_kernel(const float* __restrict__ src,
                                                          const int* __restrict__ keep,
                                                          __bf16* __restrict__ dst, int cols4) {
  int row = blockIdx.x;
  const f4* s = (const f4*)src + (size_t)keep[row] * cols4;
  bf4* d = (bf4*)dst + (size_t)row * cols4;
  for (int i = threadIdx.x; i < cols4; i += 256) {
    f4 v = s[i];
    bf4 o = {(__bf16)v[0], (__bf16)v[1], (__bf16)v[2], (__bf16)v[3]};
    d[i] = o;
  }
}

__global__ __launch_bounds__(256) void la_kernel(const int* __restrict__ keep,
                                                 const int* __restrict__ emb,
                                                 int* __restrict__ la, int m) {
  int i = blockIdx.x * 256 + threadIdx.x;
  if (i < m) la[i] = emb[keep[i]];
}

__global__ __launch_bounds__(256) void range_kernel(const int* __restrict__ starts,
                                                    const int* __restrict__ ends,
                                                    int* __restrict__ stA, int* __restrict__ enA) {
  int n = blockIdx.x;
  int t = threadIdx.x, lane = t & 63, wv = t >> 6;
  int s1 = min(starts[n * BB_ + t], starts[n * BB_ + t + 256]);
  int e1 = max(ends[n * BB_ + t], ends[n * BB_ + t + 256]);
#pragma unroll
  for (int off = 32; off; off >>= 1) {
    s1 = min(s1, __shfl_xor(s1, off));
    e1 = max(e1, __shfl_xor(e1, off));
  }
  __shared__ int ssh[4], esh[4];
  if (lane == 0) { ssh[wv] = s1; esh[wv] = e1; }
  __syncthreads();
  if (t == 0) {
    int s = ssh[0], e = esh[0];
#pragma unroll
    for (int k = 1; k < 4; ++k) { s = min(s, ssh[k]); e = max(e, esh[k]); }
    stA[n] = s; enA[n] = e;
  }
}

// ---------------- RMSNorm of input (+bf16 copy of input) ----------------
// wave per row. Aperm[j] = rms(input[fw[j]]) * w_nin ; inb[j] = bf16(input[j])
__global__ __launch_bounds__(256) void rms_in_kernel(const float* __restrict__ input,
                                                     const int* __restrict__ fw,
                                                     const float* __restrict__ wn,
                                                     __bf16* __restrict__ Aperm,
                                                     __bf16* __restrict__ inb) {
  int wv = threadIdx.x >> 6, lane = threadIdx.x & 63;
  int j = blockIdx.x * 4 + wv;
  {
    const f4* src = (const f4*)(input + (size_t)fw[j] * Hh);
    f4 v[4];
    float ss = 0.f;
#pragma unroll
    for (int c = 0; c < 4; ++c) {
      v[c] = src[c * 64 + lane];
      ss += v[c][0] * v[c][0] + v[c][1] * v[c][1] + v[c][2] * v[c][2] + v[c][3] * v[c][3];
    }
#pragma unroll
    for (int off = 32; off; off >>= 1) ss += __shfl_xor(ss, off);
    float sc = rsqrtf(ss * (1.f / Hh) + 1e-6f);
    const f4* w4 = (const f4*)wn;
    bf4* dst = (bf4*)(Aperm + (size_t)j * Hh);
#pragma unroll
    for (int c = 0; c < 4; ++c) {
      f4 w = w4[c * 64 + lane];
      bf4 o = {(__bf16)(v[c][0] * sc * w[0]), (__bf16)(v[c][1] * sc * w[1]),
               (__bf16)(v[c][2] * sc * w[2]), (__bf16)(v[c][3] * sc * w[3])};
      dst[c * 64 + lane] = o;
    }
  }
  {
    const f4* src = (const f4*)(input + (size_t)j * Hh);
    bf4* dst = (bf4*)(inb + (size_t)j * Hh);
#pragma unroll
    for (int c = 0; c < 4; ++c) {
      f4 t = src[c * 64 + lane];
      bf4 o = {(__bf16)t[0], (__bf16)t[1], (__bf16)t[2], (__bf16)t[3]};
      dst[c * 64 + lane] = o;
    }
  }
}

// ---------------- sparse masked attention, wave per query ----------------
__global__ __launch_bounds__(256) void attn_kernel(const __bf16* __restrict__ Aperm,
                                                   const __bf16* __restrict__ Bm,
                                                   const __bf16* __restrict__ Cm,
                                                   const int* __restrict__ la,
                                                   const int* __restrict__ seq_sort,
                                                   const int* __restrict__ stA,
                                                   const int* __restrict__ enA,
                                                   const int* __restrict__ fw,
                                                   __bf16* __restrict__ comb) {
  int wv = threadIdx.x >> 6, lane = threadIdx.x & 63;
  int q = blockIdx.x * 4 + wv;
  int s = seq_sort[q];
  int n = q >> 9;  // /BB_
  int st = stA[n], en = enA[n];
  const bf8* ap = (const bf8*)(Aperm + (size_t)q * Hh);
  bf8 a0 = ap[lane], a1 = ap[64 + lane];
  float af[16];
#pragma unroll
  for (int i = 0; i < 8; ++i) { af[i] = (float)a0[i]; af[8 + i] = (float)a1[i]; }
  float m = -3.4e38f, lsum = 0.f;
  float acc[8] = {0.f, 0.f, 0.f, 0.f, 0.f, 0.f, 0.f, 0.f};
  for (int base = st & ~63; base < en; base += 64) {
    int kv = base + lane;
    bool ok = (kv >= st) && (kv < en) && (la[kv] == s);
    unsigned long long msk = __ballot(ok);
    while (msk) {
      int jj = __builtin_ctzll(msk);
      msk &= msk - 1;
      int kvj = base + jj;
      const bf8* bp = (const bf8*)(Bm + (size_t)kvj * Hh);
      bf8 b0 = bp[lane], b1 = bp[64 + lane];
      float d = 0.f;
#pragma unroll
      for (int i = 0; i < 8; ++i) d += af[i] * (float)b0[i];
#pragma unroll
      for (int i = 0; i < 8; ++i) d += af[8 + i] * (float)b1[i];
#pragma unroll
      for (int off = 32; off; off >>= 1) d += __shfl_xor(d, off);
      float wgt;
      if (d > m) {
        float scale = __expf(m - d);
        lsum *= scale;
#pragma unroll
        for (int i = 0; i < 8; ++i) acc[i] *= scale;
        m = d;
        wgt = 1.f;
      } else {
        wgt = __expf(d - m);
      }
      lsum += wgt;
      const bf8* cp = (const bf8*)(Cm + (size_t)kvj * D_EMB);
      bf8 cv = cp[lane];
#pragma unroll
      for (int i = 0; i < 8; ++i) acc[i] += wgt * (float)cv[i];
    }
  }
  float inv = 1.f / lsum;
  bf8* out = (bf8*)(comb + (size_t)fw[q] * D_EMB);
  bf8 o;
#pragma unroll
  for (int i = 0; i < 8; ++i) o[i] = (__bf16)(acc[i] * inv);
  out[lane] = o;
}

// ---------------- GEMM: C[M,N] = X @ W^T, X split in two K-segments ----------------
// 128x128 tile, BK=64, 4 waves (2x2), mfma_f32_16x16x32_bf16, global_load_lds staging.
template <bool OUT_BF16>
__global__ __launch_bounds__(256, 2) void gemm_bt(const __bf16* __restrict__ x0, int k0,
                                                  const __bf16* __restrict__ x1, int k1,
                                                  const __bf16* __restrict__ w,
                                                  void* __restrict__ outp, int M, int N) {
  __shared__ __bf16 As[128 * 64];
  __shared__ __bf16 Bs[128 * 64];
  const int tid = threadIdx.x;
  const int lane = tid & 63, wv = tid >> 6;
  const int wr = wv >> 1, wc = wv & 1;
  const int m0 = blockIdx.y * 128, n0 = blockIdx.x * 128;
  const int K = k0 + k1;

  f32x4 zero = {0.f, 0.f, 0.f, 0.f};
  f32x4 acc[4][4];
#pragma unroll
  for (int a = 0; a < 4; ++a)
#pragma unroll
    for (int b = 0; b < 4; ++b) acc[a][b] = zero;

  for (int kb = 0; kb < K; kb += 64) {
    const __bf16* xs;
    int ld, kk;
    if (kb < k0) { xs = x0; ld = k0; kk = kb; }
    else         { xs = x1; ld = k1; kk = kb - k0; }
#pragma unroll
    for (int p = 0; p < 4; ++p) {
      int e = p * 256 + tid;
      int row = e >> 3, c8 = e & 7;
      gl_lds16(xs + (size_t)(m0 + row) * ld + kk + c8 * 8, (void*)(As + e * 8));
      gl_lds16(w + (size_t)(n0 + row) * K + kb + c8 * 8, (void*)(Bs + e * 8));
    }
    __syncthreads();
#pragma unroll
    for (int ks = 0; ks < 2; ++ks) {
      bf8 afr[4], bfr[4];
#pragma unroll
      for (int i = 0; i < 4; ++i) {
        afr[i] = *(const bf8*)(As + (wr * 64 + i * 16 + (lane & 15)) * 64 + ks * 32 + (lane >> 4) * 8);
        bfr[i] = *(const bf8*)(Bs + (wc * 64 + i * 16 + (lane & 15)) * 64 + ks * 32 + (lane >> 4) * 8);
      }
#pragma unroll
      for (int mi = 0; mi < 4; ++mi)
#pragma unroll
        for (int ni = 0; ni < 4; ++ni)
          acc[mi][ni] = __builtin_amdgcn_mfma_f32_16x16x32_bf16(afr[mi], bfr[ni], acc[mi][ni], 0, 0, 0);
    }
    __syncthreads();
  }
  const int r0 = (lane >> 4) * 4, cc = lane & 15;
#pragma unroll
  for (int mi = 0; mi < 4; ++mi) {
#pragma unroll
    for (int ni = 0; ni < 4; ++ni) {
      int col = n0 + wc * 64 + ni * 16 + cc;
#pragma unroll
      for (int r = 0; r < 4; ++r) {
        int row = m0 + wr * 64 + mi * 16 + r0 + r;
        float v = acc[mi][ni][r];
        if (OUT_BF16)
          ((__bf16*)outp)[(size_t)row * N + col] = (__bf16)v;
        else
          ((float*)outp)[(size_t)row * N + col] = v;
      }
    }
  }
}

// ---------------- in-place RMSNorm of up ----------------
__global__ __launch_bounds__(256) void rms_up_kernel(__bf16* __restrict__ up,
                                                     const float* __restrict__ wn) {
  int wv = threadIdx.x >> 6, lane = threadIdx.x & 63;
  size_t j = (size_t)blockIdx.x * 4 + wv;
  bf8* row = (bf8*)(up + j * D_UP);
  bf8 v[4];
  float ss = 0.f;
#pragma unroll
  for (int c = 0; c < 4; ++c) {
    v[c] = row[c * 64 + lane];
#pragma unroll
    for (int i = 0; i < 8; ++i) { float f = (float)v[c][i]; ss += f * f; }
  }
#pragma unroll
  for (int off = 32; off; off >>= 1) ss += __shfl_xor(ss, off);
  float sc = rsqrtf(ss * (1.f / D_UP) + 1e-6f);
#pragma unroll
  for (int c = 0; c < 4; ++c) {
    int ebase = (c * 64 + lane) * 8;
    f4 wa = *(const f4*)(wn + ebase);
    f4 wb = *(const f4*)(wn + ebase + 4);
    bf8 o;
#pragma unroll
    for (int i = 0; i < 4; ++i) o[i] = (__bf16)((float)v[c][i] * sc * wa[i]);
#pragma unroll
    for (int i = 0; i < 4; ++i) o[4 + i] = (__bf16)((float)v[c][4 + i] * sc * wb[i]);
    row[c * 64 + lane] = o;
  }
}

// ---------------- launch ----------------
extern "C" void kernel_launch(void* const* d_in, const int* in_sizes, int n_in, void* d_out,
                              int out_size, void* d_ws, size_t ws_size, hipStream_t stream) {
  const float* input = (const float*)d_in[0];
  const int* fw = (const int*)d_in[1];
  // d_in[2] = bw (unused: scatter via fw is its inverse)
  const int* seq_sort = (const int*)d_in[3];
  const int* keep_cols = (const int*)d_in[4];
  const int* emb_alloc = (const int*)d_in[5];
  const int* starts = (const int*)d_in[6];
  const int* ends = (const int*)d_in[7];
  // d_in[8] = bb (constant 512, hardcoded)
  const float* w_k = (const float*)d_in[9];
  const float* w_v = (const float*)d_in[10];
  const float* w_up = (const float*)d_in[11];
  const float* w_mix = (const float*)d_in[12];
  const float* w_nin = (const float*)d_in[13];
  const float* w_nout = (const float*)d_in[14];

  char* p = (char*)d_ws;
  auto take = [&](size_t b) {
    void* r = (void*)p;
    p += (b + 255) & ~(size_t)255;
    return r;
  };
  __bf16* Aperm = (__bf16*)take((size_t)BT * Hh * 2);
  __bf16* inb = (__bf16*)take((size_t)BT * Hh * 2);
  __bf16* comb = (__bf16*)take((size_t)BT * D_EMB * 2);
  __bf16* up = (__bf16*)take((size_t)BT * D_UP * 2);
  __bf16* BmB = (__bf16*)take((size_t)Mm * Hh * 2);
  __bf16* CmB = (__bf16*)take((size_t)Mm * D_EMB * 2);
  __bf16* wupB = (__bf16*)take((size_t)D_UP * D_EMB * 2);
  __bf16* wmixB = (__bf16*)take((size_t)Hh * (D_UP + Hh) * 2);
  int* la = (int*)take(Mm * 4);
  int* stA = (int*)take(NB * 4);
  int* enA = (int*)take(NB * 4);

  // prep
  conv_bf16_kernel<<<(D_UP * D_EMB / 4 + 255) / 256, 256, 0, stream>>>(w_up, wupB, D_UP * D_EMB / 4);
  conv_bf16_kernel<<<(Hh * (D_UP + Hh) / 4 + 255) / 256, 256, 0, stream>>>(w_mix, wmixB,
                                                                           Hh * (D_UP + Hh) / 4);
  gather_bf16_kernel<<<Mm, 256, 0, stream>>>(w_k, keep_cols, BmB, Hh / 4);
  gather_bf16_kernel<<<Mm, 256, 0, stream>>>(w_v, keep_cols, CmB, D_EMB / 4);
  la_kernel<<<Mm / 256, 256, 0, stream>>>(keep_cols, emb_alloc, la, Mm);
  range_kernel<<<NB, 256, 0, stream>>>(starts, ends, stA, enA);

  // pipeline
  rms_in_kernel<<<BT / 4, 256, 0, stream>>>(input, fw, w_nin, Aperm, inb);
  attn_kernel<<<BT / 4, 256, 0, stream>>>(Aperm, BmB, CmB, la, seq_sort, stA, enA, fw, comb);
  gemm_bt<true><<<dim3(D_UP / 128, BT / 128), 256, 0, stream>>>(comb, D_EMB, (const __bf16*)nullptr,
                                                                0, wupB, (void*)up, BT, D_UP);
  rms_up_kernel<<<BT / 4, 256, 0, stream>>>(up, w_nout);
  gemm_bt<false><<<dim3(Hh / 128, BT / 128), 256, 0, stream>>>(up, D_UP, inb, Hh, wmixB, d_out, BT,
                                                               Hh);
}

// Round 2
// 404.132 us; speedup vs baseline: 1.2265x; 1.2265x over previous
//
#include <hip/hip_runtime.h>
#include <hip/hip_bf16.h>
#include <cstdint>
#include <cstddef>

// ---- constants (fixed by the reference problem) ----
#define Hh 1024
#define D_EMB 512
#define D_UP 2048
#define BT 16384      // B*T
#define BB_ 512
#define Mm 4096
#define NB 32         // BT/BB
#define KL 64         // K_LABELS

typedef __attribute__((ext_vector_type(4))) float f4;
typedef __attribute__((ext_vector_type(4))) __bf16 bf4;
typedef __attribute__((ext_vector_type(8))) __bf16 bf8;
typedef __attribute__((ext_vector_type(4))) float f32x4;

// ---------------- helpers ----------------
__device__ __forceinline__ void gl_lds16(const void* g, void* l) {
  __builtin_amdgcn_global_load_lds((__attribute__((address_space(1))) void*)g,
                                   (__attribute__((address_space(3))) void*)l, 16, 0, 0);
}

// ---------------- prep kernels ----------------
__global__ __launch_bounds__(256) void conv_bf16_kernel(const float* __restrict__ src,
                                                        __bf16* __restrict__ dst, int n4) {
  int i = blockIdx.x * 256 + threadIdx.x;
  if (i >= n4) return;
  f4 v = ((const f4*)src)[i];
  bf4 o = {(__bf16)v[0], (__bf16)v[1], (__bf16)v[2], (__bf16)v[3]};
  ((bf4*)dst)[i] = o;
}

__global__ __launch_bounds__(256) void gather_bf16_kernel(const float* __restrict__ src,
                                                          const int* __restrict__ keep,
                                                          __bf16* __restrict__ dst, int cols4) {
  int row = blockIdx.x;
  const f4* s = (const f4*)src + (size_t)keep[row] * cols4;
  bf4* d = (bf4*)dst + (size_t)row * cols4;
  for (int i = threadIdx.x; i < cols4; i += 256) {
    f4 v = s[i];
    bf4 o = {(__bf16)v[0], (__bf16)v[1], (__bf16)v[2], (__bf16)v[3]};
    d[i] = o;
  }
}

__global__ __launch_bounds__(256) void la_kernel(const int* __restrict__ keep,
                                                 const int* __restrict__ emb,
                                                 int* __restrict__ la, int m) {
  int i = blockIdx.x * 256 + threadIdx.x;
  if (i < m) la[i] = emb[keep[i]];
}

__global__ __launch_bounds__(256) void range_kernel(const int* __restrict__ starts,
                                                    const int* __restrict__ ends,
                                                    int* __restrict__ stA, int* __restrict__ enA) {
  int n = blockIdx.x;
  int t = threadIdx.x, lane = t & 63, wv = t >> 6;
  int s1 = min(starts[n * BB_ + t], starts[n * BB_ + t + 256]);
  int e1 = max(ends[n * BB_ + t], ends[n * BB_ + t + 256]);
#pragma unroll
  for (int off = 32; off; off >>= 1) {
    s1 = min(s1, __shfl_xor(s1, off));
    e1 = max(e1, __shfl_xor(e1, off));
  }
  __shared__ int ssh[4], esh[4];
  if (lane == 0) { ssh[wv] = s1; esh[wv] = e1; }
  __syncthreads();
  if (t == 0) {
    int s = ssh[0], e = esh[0];
#pragma unroll
    for (int k = 1; k < 4; ++k) { s = min(s, ssh[k]); e = max(e, esh[k]); }
    stA[n] = s; enA[n] = e;
  }
}

// counting sort of queries by label within each block of 512
__global__ __launch_bounds__(256) void qsort_kernel(const int* __restrict__ seq_sort,
                                                    int* __restrict__ qidx,
                                                    int* __restrict__ qoffA,
                                                    int* __restrict__ qcntA) {
  int n = blockIdx.x, tid = threadIdx.x;
  __shared__ int cnt[KL], pos[KL], pref[KL];
  if (tid < KL) cnt[tid] = 0;
  __syncthreads();
  int s0 = seq_sort[n * BB_ + tid];
  int s1 = seq_sort[n * BB_ + tid + 256];
  atomicAdd(&cnt[s0], 1);
  atomicAdd(&cnt[s1], 1);
  __syncthreads();
  if (tid == 0) {
    int a = 0;
    for (int s = 0; s < KL; ++s) { pref[s] = a; a += cnt[s]; }
  }
  __syncthreads();
  if (tid < KL) {
    pos[tid] = pref[tid];
    qoffA[n * KL + tid] = pref[tid];
    qcntA[n * KL + tid] = cnt[tid];
  }
  __syncthreads();
  int p0 = atomicAdd(&pos[s0], 1);
  qidx[n * BB_ + p0] = n * BB_ + tid;
  int p1 = atomicAdd(&pos[s1], 1);
  qidx[n * BB_ + p1] = n * BB_ + tid + 256;
}

// counting sort of kv rows in [st,en) by label, per block
__global__ __launch_bounds__(256) void ksort_kernel(const int* __restrict__ la,
                                                    const int* __restrict__ stA,
                                                    const int* __restrict__ enA,
                                                    int* __restrict__ kidx,
                                                    int* __restrict__ koffA,
                                                    int* __restrict__ kcntA) {
  int n = blockIdx.x, tid = threadIdx.x;
  int st = stA[n], en = enA[n];
  __shared__ int cnt[KL], pos[KL], pref[KL];
  if (tid < KL) cnt[tid] = 0;
  __syncthreads();
  for (int kv = st + tid; kv < en; kv += 256) atomicAdd(&cnt[la[kv]], 1);
  __syncthreads();
  if (tid == 0) {
    int a = 0;
    for (int s = 0; s < KL; ++s) { pref[s] = a; a += cnt[s]; }
  }
  __syncthreads();
  if (tid < KL) {
    pos[tid] = pref[tid];
    koffA[n * KL + tid] = pref[tid];
    kcntA[n * KL + tid] = cnt[tid];
  }
  __syncthreads();
  for (int kv = st + tid; kv < en; kv += 256) {
    int p = atomicAdd(&pos[la[kv]], 1);
    kidx[n * Mm + p] = kv;
  }
}

// ---------------- RMSNorm of input (+bf16 copy of input) ----------------
__global__ __launch_bounds__(256) void rms_in_kernel(const float* __restrict__ input,
                                                     const int* __restrict__ fw,
                                                     const float* __restrict__ wn,
                                                     __bf16* __restrict__ Aperm,
                                                     __bf16* __restrict__ inb) {
  int wv = threadIdx.x >> 6, lane = threadIdx.x & 63;
  int j = blockIdx.x * 4 + wv;
  {
    const f4* src = (const f4*)(input + (size_t)fw[j] * Hh);
    f4 v[4];
    float ss = 0.f;
#pragma unroll
    for (int c = 0; c < 4; ++c) {
      v[c] = src[c * 64 + lane];
      ss += v[c][0] * v[c][0] + v[c][1] * v[c][1] + v[c][2] * v[c][2] + v[c][3] * v[c][3];
    }
#pragma unroll
    for (int off = 32; off; off >>= 1) ss += __shfl_xor(ss, off);
    float sc = rsqrtf(ss * (1.f / Hh) + 1e-6f);
    const f4* w4 = (const f4*)wn;
    bf4* dst = (bf4*)(Aperm + (size_t)j * Hh);
#pragma unroll
    for (int c = 0; c < 4; ++c) {
      f4 w = w4[c * 64 + lane];
      bf4 o = {(__bf16)(v[c][0] * sc * w[0]), (__bf16)(v[c][1] * sc * w[1]),
               (__bf16)(v[c][2] * sc * w[2]), (__bf16)(v[c][3] * sc * w[3])};
      dst[c * 64 + lane] = o;
    }
  }
  {
    const f4* src = (const f4*)(input + (size_t)j * Hh);
    bf4* dst = (bf4*)(inb + (size_t)j * Hh);
#pragma unroll
    for (int c = 0; c < 4; ++c) {
      f4 t = src[c * 64 + lane];
      bf4 o = {(__bf16)t[0], (__bf16)t[1], (__bf16)t[2], (__bf16)t[3]};
      dst[c * 64 + lane] = o;
    }
  }
}

// ---------------- grouped MFMA attention ----------------
// one workgroup (4 waves) per (block, label) group. MFMA QK^T, VALU softmax+PV.
__global__ __launch_bounds__(256) void attn2_kernel(const __bf16* __restrict__ Aperm,
                                                    const __bf16* __restrict__ Bm,
                                                    const __bf16* __restrict__ Cm,
                                                    const int* __restrict__ qidx,
                                                    const int* __restrict__ qoffA,
                                                    const int* __restrict__ qcntA,
                                                    const int* __restrict__ kidx,
                                                    const int* __restrict__ koffA,
                                                    const int* __restrict__ kcntA,
                                                    const int* __restrict__ fw,
                                                    __bf16* __restrict__ comb) {
  int g = blockIdx.x;
  int n = g >> 6;
  int qcnt = qcntA[g];
  if (qcnt == 0) return;
  int kcnt = kcntA[g];
  int qbase = n * BB_ + qoffA[g];
  int kbase = n * Mm + koffA[g];
  int tid = threadIdx.x, lane = tid & 63, wv = tid >> 6;
  int c = lane & 15, rg = lane >> 4;
  __shared__ float Sbuf[16][66];

  for (int qt = 0; qt < qcnt; qt += 16) {
    int ql = qt + c;
    int j = qidx[qbase + (ql < qcnt ? ql : 0)];
    const __bf16* arow = Aperm + (size_t)j * Hh + rg * 8;

    float m[4] = {-1e30f, -1e30f, -1e30f, -1e30f};
    float l[4] = {0.f, 0.f, 0.f, 0.f};
    float acc[4][8];
#pragma unroll
    for (int r = 0; r < 4; ++r)
#pragma unroll
      for (int i = 0; i < 8; ++i) acc[r][i] = 0.f;

    int nch = (kcnt + 63) >> 6;
    for (int ch = 0; ch < nch; ++ch) {
      int posk = ch * 64 + wv * 16 + c;
      int kvr = (posk < kcnt) ? kidx[kbase + posk] : 0;
      const __bf16* brow = Bm + (size_t)kvr * Hh + rg * 8;
      f32x4 sacc = {0.f, 0.f, 0.f, 0.f};
#pragma unroll
      for (int ks = 0; ks < 32; ++ks) {
        bf8 af = *(const bf8*)(arow + ks * 32);
        bf8 bf_ = *(const bf8*)(brow + ks * 32);
        sacc = __builtin_amdgcn_mfma_f32_16x16x32_bf16(af, bf_, sacc, 0, 0, 0);
      }
      bool valid = posk < kcnt;
#pragma unroll
      for (int r = 0; r < 4; ++r) Sbuf[rg * 4 + r][wv * 16 + c] = valid ? sacc[r] : -1e30f;
      __syncthreads();

      // wave wv owns q rows wv*4 .. wv*4+3; lane -> kv position ch*64+lane
      int nval = min(64, kcnt - ch * 64);
      int kvl = (ch * 64 + lane < kcnt) ? kidx[kbase + ch * 64 + lane] : 0;
      float p[4];
#pragma unroll
      for (int r = 0; r < 4; ++r) {
        float s = Sbuf[wv * 4 + r][lane];
        float cm = s;
#pragma unroll
        for (int off = 32; off; off >>= 1) cm = fmaxf(cm, __shfl_xor(cm, off));
        float mn = fmaxf(m[r], cm);
        float sc = __expf(m[r] - mn);
        float pv = __expf(s - mn);
        float ssum = pv;
#pragma unroll
        for (int off = 32; off; off >>= 1) ssum += __shfl_xor(ssum, off);
        l[r] = l[r] * sc + ssum;
        m[r] = mn;
        p[r] = pv;
#pragma unroll
        for (int i = 0; i < 8; ++i) acc[r][i] *= sc;
      }
      for (int jj = 0; jj < nval; ++jj) {
        int kvr2 = __shfl(kvl, jj);
        bf8 v = *(const bf8*)(Cm + (size_t)kvr2 * D_EMB + lane * 8);
        float vf[8];
#pragma unroll
        for (int i = 0; i < 8; ++i) vf[i] = (float)v[i];
        float p0 = __shfl(p[0], jj), p1 = __shfl(p[1], jj);
        float p2 = __shfl(p[2], jj), p3 = __shfl(p[3], jj);
#pragma unroll
        for (int i = 0; i < 8; ++i) {
          acc[0][i] += p0 * vf[i];
          acc[1][i] += p1 * vf[i];
          acc[2][i] += p2 * vf[i];
          acc[3][i] += p3 * vf[i];
        }
      }
      __syncthreads();
    }
    // store owned rows
#pragma unroll
    for (int r = 0; r < 4; ++r) {
      int ql2 = qt + wv * 4 + r;
      if (ql2 < qcnt) {
        int j2 = qidx[qbase + ql2];
        float inv = 1.f / l[r];
        bf8 o;
#pragma unroll
        for (int i = 0; i < 8; ++i) o[i] = (__bf16)(acc[r][i] * inv);
        *(bf8*)(comb + (size_t)fw[j2] * D_EMB + lane * 8) = o;
      }
    }
  }
}

// ---------------- GEMM: C[M,N] = X @ W^T, X split in two K-segments ----------------
template <bool OUT_BF16>
__global__ __launch_bounds__(256, 2) void gemm_bt(const __bf16* __restrict__ x0, int k0,
                                                  const __bf16* __restrict__ x1, int k1,
                                                  const __bf16* __restrict__ w,
                                                  void* __restrict__ outp, int M, int N) {
  __shared__ __bf16 As[128 * 64];
  __shared__ __bf16 Bs[128 * 64];
  const int tid = threadIdx.x;
  const int lane = tid & 63, wv = tid >> 6;
  const int wr = wv >> 1, wc = wv & 1;
  const int m0 = blockIdx.y * 128, n0 = blockIdx.x * 128;
  const int K = k0 + k1;

  f32x4 zero = {0.f, 0.f, 0.f, 0.f};
  f32x4 acc[4][4];
#pragma unroll
  for (int a = 0; a < 4; ++a)
#pragma unroll
    for (int b = 0; b < 4; ++b) acc[a][b] = zero;

  for (int kb = 0; kb < K; kb += 64) {
    const __bf16* xs;
    int ld, kk;
    if (kb < k0) { xs = x0; ld = k0; kk = kb; }
    else         { xs = x1; ld = k1; kk = kb - k0; }
#pragma unroll
    for (int p = 0; p < 4; ++p) {
      int e = p * 256 + tid;
      int row = e >> 3, c8 = e & 7;
      gl_lds16(xs + (size_t)(m0 + row) * ld + kk + c8 * 8, (void*)(As + e * 8));
      gl_lds16(w + (size_t)(n0 + row) * K + kb + c8 * 8, (void*)(Bs + e * 8));
    }
    __syncthreads();
#pragma unroll
    for (int ks = 0; ks < 2; ++ks) {
      bf8 afr[4], bfr[4];
#pragma unroll
      for (int i = 0; i < 4; ++i) {
        afr[i] = *(const bf8*)(As + (wr * 64 + i * 16 + (lane & 15)) * 64 + ks * 32 + (lane >> 4) * 8);
        bfr[i] = *(const bf8*)(Bs + (wc * 64 + i * 16 + (lane & 15)) * 64 + ks * 32 + (lane >> 4) * 8);
      }
#pragma unroll
      for (int mi = 0; mi < 4; ++mi)
#pragma unroll
        for (int ni = 0; ni < 4; ++ni)
          acc[mi][ni] = __builtin_amdgcn_mfma_f32_16x16x32_bf16(afr[mi], bfr[ni], acc[mi][ni], 0, 0, 0);
    }
    __syncthreads();
  }
  const int r0 = (lane >> 4) * 4, cc = lane & 15;
#pragma unroll
  for (int mi = 0; mi < 4; ++mi) {
#pragma unroll
    for (int ni = 0; ni < 4; ++ni) {
      int col = n0 + wc * 64 + ni * 16 + cc;
#pragma unroll
      for (int r = 0; r < 4; ++r) {
        int row = m0 + wr * 64 + mi * 16 + r0 + r;
        float v = acc[mi][ni][r];
        if (OUT_BF16)
          ((__bf16*)outp)[(size_t)row * N + col] = (__bf16)v;
        else
          ((float*)outp)[(size_t)row * N + col] = v;
      }
    }
  }
}

// ---------------- in-place RMSNorm of up ----------------
__global__ __launch_bounds__(256) void rms_up_kernel(__bf16* __restrict__ up,
                                                     const float* __restrict__ wn) {
  int wv = threadIdx.x >> 6, lane = threadIdx.x & 63;
  size_t j = (size_t)blockIdx.x * 4 + wv;
  bf8* row = (bf8*)(up + j * D_UP);
  bf8 v[4];
  float ss = 0.f;
#pragma unroll
  for (int c = 0; c < 4; ++c) {
    v[c] = row[c * 64 + lane];
#pragma unroll
    for (int i = 0; i < 8; ++i) { float f = (float)v[c][i]; ss += f * f; }
  }
#pragma unroll
  for (int off = 32; off; off >>= 1) ss += __shfl_xor(ss, off);
  float sc = rsqrtf(ss * (1.f / D_UP) + 1e-6f);
#pragma unroll
  for (int c = 0; c < 4; ++c) {
    int ebase = (c * 64 + lane) * 8;
    f4 wa = *(const f4*)(wn + ebase);
    f4 wb = *(const f4*)(wn + ebase + 4);
    bf8 o;
#pragma unroll
    for (int i = 0; i < 4; ++i) o[i] = (__bf16)((float)v[c][i] * sc * wa[i]);
#pragma unroll
    for (int i = 0; i < 4; ++i) o[4 + i] = (__bf16)((float)v[c][4 + i] * sc * wb[i]);
    row[c * 64 + lane] = o;
  }
}

// ---------------- launch ----------------
extern "C" void kernel_launch(void* const* d_in, const int* in_sizes, int n_in, void* d_out,
                              int out_size, void* d_ws, size_t ws_size, hipStream_t stream) {
  const float* input = (const float*)d_in[0];
  const int* fw = (const int*)d_in[1];
  const int* seq_sort = (const int*)d_in[3];
  const int* keep_cols = (const int*)d_in[4];
  const int* emb_alloc = (const int*)d_in[5];
  const int* starts = (const int*)d_in[6];
  const int* ends = (const int*)d_in[7];
  const float* w_k = (const float*)d_in[9];
  const float* w_v = (const float*)d_in[10];
  const float* w_up = (const float*)d_in[11];
  const float* w_mix = (const float*)d_in[12];
  const float* w_nin = (const float*)d_in[13];
  const float* w_nout = (const float*)d_in[14];

  char* p = (char*)d_ws;
  auto take = [&](size_t b) {
    void* r = (void*)p;
    p += (b + 255) & ~(size_t)255;
    return r;
  };
  __bf16* Aperm = (__bf16*)take((size_t)BT * Hh * 2);
  __bf16* inb = (__bf16*)take((size_t)BT * Hh * 2);
  __bf16* comb = (__bf16*)take((size_t)BT * D_EMB * 2);
  __bf16* up = (__bf16*)take((size_t)BT * D_UP * 2);
  __bf16* BmB = (__bf16*)take((size_t)Mm * Hh * 2);
  __bf16* CmB = (__bf16*)take((size_t)Mm * D_EMB * 2);
  __bf16* wupB = (__bf16*)take((size_t)D_UP * D_EMB * 2);
  __bf16* wmixB = (__bf16*)take((size_t)Hh * (D_UP + Hh) * 2);
  int* la = (int*)take(Mm * 4);
  int* stA = (int*)take(NB * 4);
  int* enA = (int*)take(NB * 4);
  int* qidx = (int*)take(BT * 4);
  int* qoffA = (int*)take(NB * KL * 4);
  int* qcntA = (int*)take(NB * KL * 4);
  int* kidx = (int*)take((size_t)NB * Mm * 4);
  int* koffA = (int*)take(NB * KL * 4);
  int* kcntA = (int*)take(NB * KL * 4);

  // prep
  conv_bf16_kernel<<<(D_UP * D_EMB / 4 + 255) / 256, 256, 0, stream>>>(w_up, wupB, D_UP * D_EMB / 4);
  conv_bf16_kernel<<<(Hh * (D_UP + Hh) / 4 + 255) / 256, 256, 0, stream>>>(w_mix, wmixB,
                                                                           Hh * (D_UP + Hh) / 4);
  gather_bf16_kernel<<<Mm, 256, 0, stream>>>(w_k, keep_cols, BmB, Hh / 4);
  gather_bf16_kernel<<<Mm, 256, 0, stream>>>(w_v, keep_cols, CmB, D_EMB / 4);
  la_kernel<<<Mm / 256, 256, 0, stream>>>(keep_cols, emb_alloc, la, Mm);
  range_kernel<<<NB, 256, 0, stream>>>(starts, ends, stA, enA);
  qsort_kernel<<<NB, 256, 0, stream>>>(seq_sort, qidx, qoffA, qcntA);
  ksort_kernel<<<NB, 256, 0, stream>>>(la, stA, enA, kidx, koffA, kcntA);

  // pipeline
  rms_in_kernel<<<BT / 4, 256, 0, stream>>>(input, fw, w_nin, Aperm, inb);
  attn2_kernel<<<NB * KL, 256, 0, stream>>>(Aperm, BmB, CmB, qidx, qoffA, qcntA, kidx, koffA,
                                            kcntA, fw, comb);
  gemm_bt<true><<<dim3(D_UP / 128, BT / 128), 256, 0, stream>>>(comb, D_EMB, (const __bf16*)nullptr,
                                                                0, wupB, (void*)up, BT, D_UP);
  rms_up_kernel<<<BT / 4, 256, 0, stream>>>(up, w_nout);
  gemm_bt<false><<<dim3(Hh / 128, BT / 128), 256, 0, stream>>>(up, D_UP, inb, Hh, wmixB, d_out, BT,
                                                               Hh);
}

// Round 3
// 364.812 us; speedup vs baseline: 1.3587x; 1.1078x over previous
//
#include <hip/hip_runtime.h>
#include <hip/hip_bf16.h>
#include <cstdint>
#include <cstddef>

// ---- constants (fixed by the reference problem) ----
#define Hh 1024
#define D_EMB 512
#define D_UP 2048
#define BT 16384      // B*T
#define BB_ 512
#define Mm 4096
#define MmP 4160      // Mm + 64 pad rows/cols for chunk-tail overreads
#define NB 32         // BT/BB
#define KL 64         // K_LABELS

typedef __attribute__((ext_vector_type(4))) float f4;
typedef __attribute__((ext_vector_type(4))) __bf16 bf4;
typedef __attribute__((ext_vector_type(8))) __bf16 bf8;
typedef __attribute__((ext_vector_type(4))) float f32x4;

// ---------------- helpers ----------------
__device__ __forceinline__ void gl_lds16(const void* g, void* l) {
  __builtin_amdgcn_global_load_lds((__attribute__((address_space(1))) void*)g,
                                   (__attribute__((address_space(3))) void*)l, 16, 0, 0);
}

// ---------------- prep kernels ----------------
__global__ __launch_bounds__(256) void conv_bf16_kernel(const float* __restrict__ src,
                                                        __bf16* __restrict__ dst, int n4) {
  int i = blockIdx.x * 256 + threadIdx.x;
  if (i >= n4) return;
  f4 v = ((const f4*)src)[i];
  bf4 o = {(__bf16)v[0], (__bf16)v[1], (__bf16)v[2], (__bf16)v[3]};
  ((bf4*)dst)[i] = o;
}

__global__ __launch_bounds__(256) void gather_bf16_kernel(const float* __restrict__ src,
                                                          const int* __restrict__ idx,
                                                          __bf16* __restrict__ dst, int cols4) {
  int row = blockIdx.x;
  const f4* s = (const f4*)src + (size_t)idx[row] * cols4;
  bf4* d = (bf4*)dst + (size_t)row * cols4;
  for (int i = threadIdx.x; i < cols4; i += 256) {
    f4 v = s[i];
    bf4 o = {(__bf16)v[0], (__bf16)v[1], (__bf16)v[2], (__bf16)v[3]};
    d[i] = o;
  }
}

__global__ __launch_bounds__(256) void la_kernel(const int* __restrict__ keep,
                                                 const int* __restrict__ emb,
                                                 int* __restrict__ la, int m) {
  int i = blockIdx.x * 256 + threadIdx.x;
  if (i < m) la[i] = emb[keep[i]];
}

__global__ __launch_bounds__(256) void range_kernel(const int* __restrict__ starts,
                                                    const int* __restrict__ ends,
                                                    int* __restrict__ stA, int* __restrict__ enA) {
  int n = blockIdx.x;
  int t = threadIdx.x, lane = t & 63, wv = t >> 6;
  int s1 = min(starts[n * BB_ + t], starts[n * BB_ + t + 256]);
  int e1 = max(ends[n * BB_ + t], ends[n * BB_ + t + 256]);
#pragma unroll
  for (int off = 32; off; off >>= 1) {
    s1 = min(s1, __shfl_xor(s1, off));
    e1 = max(e1, __shfl_xor(e1, off));
  }
  __shared__ int ssh[4], esh[4];
  if (lane == 0) { ssh[wv] = s1; esh[wv] = e1; }
  __syncthreads();
  if (t == 0) {
    int s = ssh[0], e = esh[0];
#pragma unroll
    for (int k = 1; k < 4; ++k) { s = min(s, ssh[k]); e = max(e, esh[k]); }
    stA[n] = s; enA[n] = e;
  }
}

// histogram of labels over all Mm rows + exclusive prefix -> goff[KL+1]
__global__ __launch_bounds__(256) void hist_kernel(const int* __restrict__ la,
                                                   int* __restrict__ goff) {
  __shared__ int cnt[KL];
  int tid = threadIdx.x;
  if (tid < KL) cnt[tid] = 0;
  __syncthreads();
  for (int k = tid; k < Mm; k += 256) atomicAdd(&cnt[la[k]], 1);
  __syncthreads();
  if (tid == 0) {
    int a = 0;
    for (int s = 0; s < KL; ++s) { goff[s] = a; a += cnt[s]; }
    goff[KL] = a;
  }
}

// stable placement: global sorted-by-(label,k) order. one wg per label.
__global__ __launch_bounds__(256) void place_kernel(const int* __restrict__ la,
                                                    const int* __restrict__ keep,
                                                    const int* __restrict__ goff,
                                                    int* __restrict__ gk,
                                                    int* __restrict__ ridx) {
  int s = blockIdx.x;
  int tid = threadIdx.x, lane = tid & 63, wv = tid >> 6;
  __shared__ int wc[4];
  __shared__ int run;
  if (tid == 0) run = goff[s];
  __syncthreads();
  for (int base = 0; base < Mm; base += 256) {
    int k = base + tid;
    bool f = (la[k] == s);
    unsigned long long msk = __ballot(f);
    int myidx = __popcll(msk & ((1ull << lane) - 1ull));
    if (lane == 0) wc[wv] = __popcll(msk);
    __syncthreads();
    int woff = 0, tot = 0;
#pragma unroll
    for (int w = 0; w < 4; ++w) {
      if (w < wv) woff += wc[w];
      tot += wc[w];
    }
    int rbase = run;
    if (f) {
      int p = rbase + woff + myidx;
      gk[p] = k;
      ridx[p] = keep[k];
    }
    __syncthreads();
    if (tid == 0) run = rbase + tot;
    __syncthreads();
  }
}

// per (block,label): contiguous sorted-pos range [lo,hi)
__global__ __launch_bounds__(256) void lohi_kernel(const int* __restrict__ gk,
                                                   const int* __restrict__ goff,
                                                   const int* __restrict__ stA,
                                                   const int* __restrict__ enA,
                                                   int* __restrict__ loA, int* __restrict__ hiA) {
  int i = blockIdx.x * 256 + threadIdx.x;
  if (i >= NB * KL) return;
  int n = i / KL, s = i % KL;
  int b = goff[s], e = goff[s + 1];
  int st = stA[n], en = enA[n];
  int lo = b, hi = e;
  while (lo < hi) { int mid = (lo + hi) >> 1; if (gk[mid] < st) lo = mid + 1; else hi = mid; }
  int L = lo;
  lo = b; hi = e;
  while (lo < hi) { int mid = (lo + hi) >> 1; if (gk[mid] < en) lo = mid + 1; else hi = mid; }
  loA[i] = L;
  hiA[i] = lo;
}

// VT[d][pos] = bf16(w_v[ridx[pos]][d]) via LDS tile transpose
__global__ __launch_bounds__(256) void vt_kernel(const float* __restrict__ wv_,
                                                 const int* __restrict__ ridx,
                                                 __bf16* __restrict__ VT) {
  int pb = blockIdx.x * 64;
  int db = blockIdx.y * 64;
  __shared__ float T[64][65];
  int t = threadIdx.x;
  int dl = t & 63, g = t >> 6;
  for (int i = g * 16; i < g * 16 + 16; ++i) {
    int r = ridx[pb + i];
    T[dl][i] = wv_[(size_t)r * D_EMB + db + dl];
  }
  __syncthreads();
  int pl = t & 63;
  for (int j = g * 16; j < g * 16 + 16; ++j) {
    VT[(size_t)(db + j) * MmP + pb + pl] = (__bf16)T[j][pl];
  }
}

// counting sort of queries by label within each block of 512
__global__ __launch_bounds__(256) void qsort_kernel(const int* __restrict__ seq_sort,
                                                    int* __restrict__ qidx,
                                                    int* __restrict__ qoffA,
                                                    int* __restrict__ qcntA) {
  int n = blockIdx.x, tid = threadIdx.x;
  __shared__ int cnt[KL], pos[KL], pref[KL];
  if (tid < KL) cnt[tid] = 0;
  __syncthreads();
  int s0 = seq_sort[n * BB_ + tid];
  int s1 = seq_sort[n * BB_ + tid + 256];
  atomicAdd(&cnt[s0], 1);
  atomicAdd(&cnt[s1], 1);
  __syncthreads();
  if (tid == 0) {
    int a = 0;
    for (int s = 0; s < KL; ++s) { pref[s] = a; a += cnt[s]; }
  }
  __syncthreads();
  if (tid < KL) {
    pos[tid] = pref[tid];
    qoffA[n * KL + tid] = pref[tid];
    qcntA[n * KL + tid] = cnt[tid];
  }
  __syncthreads();
  int p0 = atomicAdd(&pos[s0], 1);
  qidx[n * BB_ + p0] = n * BB_ + tid;
  int p1 = atomicAdd(&pos[s1], 1);
  qidx[n * BB_ + p1] = n * BB_ + tid + 256;
}

// ---------------- RMSNorm of input (+bf16 copy of input) ----------------
__global__ __launch_bounds__(256) void rms_in_kernel(const float* __restrict__ input,
                                                     const int* __restrict__ fw,
                                                     const float* __restrict__ wn,
                                                     __bf16* __restrict__ Aperm,
                                                     __bf16* __restrict__ inb) {
  int wv = threadIdx.x >> 6, lane = threadIdx.x & 63;
  int j = blockIdx.x * 4 + wv;
  {
    const f4* src = (const f4*)(input + (size_t)fw[j] * Hh);
    f4 v[4];
    float ss = 0.f;
#pragma unroll
    for (int c = 0; c < 4; ++c) {
      v[c] = src[c * 64 + lane];
      ss += v[c][0] * v[c][0] + v[c][1] * v[c][1] + v[c][2] * v[c][2] + v[c][3] * v[c][3];
    }
#pragma unroll
    for (int off = 32; off; off >>= 1) ss += __shfl_xor(ss, off);
    float sc = rsqrtf(ss * (1.f / Hh) + 1e-6f);
    const f4* w4 = (const f4*)wn;
    bf4* dst = (bf4*)(Aperm + (size_t)j * Hh);
#pragma unroll
    for (int c = 0; c < 4; ++c) {
      f4 w = w4[c * 64 + lane];
      bf4 o = {(__bf16)(v[c][0] * sc * w[0]), (__bf16)(v[c][1] * sc * w[1]),
               (__bf16)(v[c][2] * sc * w[2]), (__bf16)(v[c][3] * sc * w[3])};
      dst[c * 64 + lane] = o;
    }
  }
  {
    const f4* src = (const f4*)(input + (size_t)j * Hh);
    bf4* dst = (bf4*)(inb + (size_t)j * Hh);
#pragma unroll
    for (int c = 0; c < 4; ++c) {
      f4 t = src[c * 64 + lane];
      bf4 o = {(__bf16)t[0], (__bf16)t[1], (__bf16)t[2], (__bf16)t[3]};
      dst[c * 64 + lane] = o;
    }
  }
}

// ---------------- grouped all-MFMA attention ----------------
// one workgroup (4 waves) per (block,label). kv range contiguous in sorted-pos space.
// QK^T: A=Q rows, B=Ks rows (pos).  PV: A=P (LDS), B=VT[d][pos] contiguous.
__global__ __launch_bounds__(256) void attn3_kernel(const __bf16* __restrict__ Aperm,
                                                    const __bf16* __restrict__ Ks,
                                                    const __bf16* __restrict__ VT,
                                                    const int* __restrict__ qidx,
                                                    const int* __restrict__ qoffA,
                                                    const int* __restrict__ qcntA,
                                                    const int* __restrict__ loA,
                                                    const int* __restrict__ hiA,
                                                    const int* __restrict__ fw,
                                                    __bf16* __restrict__ comb) {
  int g = blockIdx.x;
  int qcnt = qcntA[g];
  if (qcnt == 0) return;
  int n = g >> 6;
  int qbase = n * BB_ + qoffA[g];
  int lo = loA[g], hi = hiA[g];
  if (lo >= hi) return;
  int tid = threadIdx.x, lane = tid & 63, wv = tid >> 6;
  int c = lane & 15, rg = lane >> 4;
  __shared__ float Sbuf[16][66];
  __shared__ __align__(16) __bf16 Plds[16][72];
  __shared__ float scl[16], lrec[16];

  for (int qt = 0; qt < qcnt; qt += 16) {
    int ql = qt + c;
    int j = qidx[qbase + (ql < qcnt ? ql : 0)];
    const __bf16* arow = Aperm + (size_t)j * Hh + rg * 8;

    float m[4] = {-1e30f, -1e30f, -1e30f, -1e30f};
    float l[4] = {0.f, 0.f, 0.f, 0.f};
    f32x4 acc[8];
    f32x4 zero = {0.f, 0.f, 0.f, 0.f};
#pragma unroll
    for (int t8 = 0; t8 < 8; ++t8) acc[t8] = zero;

    for (int p0 = lo; p0 < hi; p0 += 64) {
      // ---- QK^T: wave wv computes S tile [16 q][16 kv] for kv = p0+wv*16.. ----
      int kvcol = p0 + wv * 16 + c;
      const __bf16* brow = Ks + (size_t)kvcol * Hh + rg * 8;
      f32x4 sacc = zero;
#pragma unroll
      for (int ks = 0; ks < 32; ++ks) {
        bf8 af = *(const bf8*)(arow + ks * 32);
        bf8 bf_ = *(const bf8*)(brow + ks * 32);
        sacc = __builtin_amdgcn_mfma_f32_16x16x32_bf16(af, bf_, sacc, 0, 0, 0);
      }
      bool valid = kvcol < hi;
#pragma unroll
      for (int r = 0; r < 4; ++r) Sbuf[rg * 4 + r][wv * 16 + c] = valid ? sacc[r] : -1e30f;
      __syncthreads();

      // ---- online softmax: wave wv owns q rows wv*4..wv*4+3, lane = kv ----
#pragma unroll
      for (int r = 0; r < 4; ++r) {
        int q = wv * 4 + r;
        float s = Sbuf[q][lane];
        float cm = s;
#pragma unroll
        for (int off = 32; off; off >>= 1) cm = fmaxf(cm, __shfl_xor(cm, off));
        float mn = fmaxf(m[r], cm);
        float sc = __expf(m[r] - mn);
        float pv = __expf(s - mn);  // s = -1e30 -> 0
        float ssum = pv;
#pragma unroll
        for (int off = 32; off; off >>= 1) ssum += __shfl_xor(ssum, off);
        l[r] = l[r] * sc + ssum;
        m[r] = mn;
        Plds[q][lane] = (__bf16)pv;
        if (lane == 0) scl[q] = sc;
      }
      __syncthreads();

      // ---- rescale accumulators (rows of acc are q = rg*4 + r) ----
      float sf[4];
#pragma unroll
      for (int r = 0; r < 4; ++r) sf[r] = scl[rg * 4 + r];
#pragma unroll
      for (int t8 = 0; t8 < 8; ++t8)
#pragma unroll
        for (int r = 0; r < 4; ++r) acc[t8][r] *= sf[r];

      // ---- PV: A = P from LDS, B = VT columns (contiguous in pos) ----
      bf8 pa0 = *(const bf8*)(&Plds[c][rg * 8]);
      bf8 pa1 = *(const bf8*)(&Plds[c][32 + rg * 8]);
#pragma unroll
      for (int tt = 0; tt < 8; ++tt) {
        int d = wv * 128 + tt * 16 + c;
        const __bf16* vrow = VT + (size_t)d * MmP + p0 + rg * 8;
        bf8 b0 = *(const bf8*)(vrow);
        bf8 b1 = *(const bf8*)(vrow + 32);
        acc[tt] = __builtin_amdgcn_mfma_f32_16x16x32_bf16(pa0, b0, acc[tt], 0, 0, 0);
        acc[tt] = __builtin_amdgcn_mfma_f32_16x16x32_bf16(pa1, b1, acc[tt], 0, 0, 0);
      }
      __syncthreads();  // protect Sbuf/Plds for next chunk
    }

    // ---- epilogue: normalize + scatter ----
    if (lane == 0) {
#pragma unroll
      for (int r = 0; r < 4; ++r) lrec[wv * 4 + r] = l[r];
    }
    __syncthreads();
    float inv[4];
    size_t obase[4];
    bool oval[4];
#pragma unroll
    for (int r = 0; r < 4; ++r) {
      int qq = qt + rg * 4 + r;
      oval[r] = qq < qcnt;
      int j2 = qidx[qbase + (oval[r] ? qq : 0)];
      obase[r] = (size_t)fw[j2] * D_EMB;
      float lv = lrec[rg * 4 + r];
      inv[r] = 1.f / lv;
    }
#pragma unroll
    for (int tt = 0; tt < 8; ++tt) {
      int d = wv * 128 + tt * 16 + c;
#pragma unroll
      for (int r = 0; r < 4; ++r) {
        if (oval[r]) comb[obase[r] + d] = (__bf16)(acc[tt][r] * inv[r]);
      }
    }
    __syncthreads();  // lrec/Sbuf reuse across q-tiles
  }
}

// ---------------- GEMM: C[M,N] = X @ W^T, X split in two K-segments ----------------
template <bool OUT_BF16>
__global__ __launch_bounds__(256, 2) void gemm_bt(const __bf16* __restrict__ x0, int k0,
                                                  const __bf16* __restrict__ x1, int k1,
                                                  const __bf16* __restrict__ w,
                                                  void* __restrict__ outp, int M, int N) {
  __shared__ __bf16 As[128 * 64];
  __shared__ __bf16 Bs[128 * 64];
  const int tid = threadIdx.x;
  const int lane = tid & 63, wv = tid >> 6;
  const int wr = wv >> 1, wc = wv & 1;
  const int m0 = blockIdx.y * 128, n0 = blockIdx.x * 128;
  const int K = k0 + k1;

  f32x4 zero = {0.f, 0.f, 0.f, 0.f};
  f32x4 acc[4][4];
#pragma unroll
  for (int a = 0; a < 4; ++a)
#pragma unroll
    for (int b = 0; b < 4; ++b) acc[a][b] = zero;

  for (int kb = 0; kb < K; kb += 64) {
    const __bf16* xs;
    int ld, kk;
    if (kb < k0) { xs = x0; ld = k0; kk = kb; }
    else         { xs = x1; ld = k1; kk = kb - k0; }
#pragma unroll
    for (int p = 0; p < 4; ++p) {
      int e = p * 256 + tid;
      int row = e >> 3, c8 = e & 7;
      gl_lds16(xs + (size_t)(m0 + row) * ld + kk + c8 * 8, (void*)(As + e * 8));
      gl_lds16(w + (size_t)(n0 + row) * K + kb + c8 * 8, (void*)(Bs + e * 8));
    }
    __syncthreads();
#pragma unroll
    for (int ks = 0; ks < 2; ++ks) {
      bf8 afr[4], bfr[4];
#pragma unroll
      for (int i = 0; i < 4; ++i) {
        afr[i] = *(const bf8*)(As + (wr * 64 + i * 16 + (lane & 15)) * 64 + ks * 32 + (lane >> 4) * 8);
        bfr[i] = *(const bf8*)(Bs + (wc * 64 + i * 16 + (lane & 15)) * 64 + ks * 32 + (lane >> 4) * 8);
      }
#pragma unroll
      for (int mi = 0; mi < 4; ++mi)
#pragma unroll
        for (int ni = 0; ni < 4; ++ni)
          acc[mi][ni] = __builtin_amdgcn_mfma_f32_16x16x32_bf16(afr[mi], bfr[ni], acc[mi][ni], 0, 0, 0);
    }
    __syncthreads();
  }
  const int r0 = (lane >> 4) * 4, cc = lane & 15;
#pragma unroll
  for (int mi = 0; mi < 4; ++mi) {
#pragma unroll
    for (int ni = 0; ni < 4; ++ni) {
      int col = n0 + wc * 64 + ni * 16 + cc;
#pragma unroll
      for (int r = 0; r < 4; ++r) {
        int row = m0 + wr * 64 + mi * 16 + r0 + r;
        float v = acc[mi][ni][r];
        if (OUT_BF16)
          ((__bf16*)outp)[(size_t)row * N + col] = (__bf16)v;
        else
          ((float*)outp)[(size_t)row * N + col] = v;
      }
    }
  }
}

// ---------------- in-place RMSNorm of up ----------------
__global__ __launch_bounds__(256) void rms_up_kernel(__bf16* __restrict__ up,
                                                     const float* __restrict__ wn) {
  int wv = threadIdx.x >> 6, lane = threadIdx.x & 63;
  size_t j = (size_t)blockIdx.x * 4 + wv;
  bf8* row = (bf8*)(up + j * D_UP);
  bf8 v[4];
  float ss = 0.f;
#pragma unroll
  for (int c = 0; c < 4; ++c) {
    v[c] = row[c * 64 + lane];
#pragma unroll
    for (int i = 0; i < 8; ++i) { float f = (float)v[c][i]; ss += f * f; }
  }
#pragma unroll
  for (int off = 32; off; off >>= 1) ss += __shfl_xor(ss, off);
  float sc = rsqrtf(ss * (1.f / D_UP) + 1e-6f);
#pragma unroll
  for (int c = 0; c < 4; ++c) {
    int ebase = (c * 64 + lane) * 8;
    f4 wa = *(const f4*)(wn + ebase);
    f4 wb = *(const f4*)(wn + ebase + 4);
    bf8 o;
#pragma unroll
    for (int i = 0; i < 4; ++i) o[i] = (__bf16)((float)v[c][i] * sc * wa[i]);
#pragma unroll
    for (int i = 0; i < 4; ++i) o[4 + i] = (__bf16)((float)v[c][4 + i] * sc * wb[i]);
    row[c * 64 + lane] = o;
  }
}

// ---------------- launch ----------------
extern "C" void kernel_launch(void* const* d_in, const int* in_sizes, int n_in, void* d_out,
                              int out_size, void* d_ws, size_t ws_size, hipStream_t stream) {
  const float* input = (const float*)d_in[0];
  const int* fw = (const int*)d_in[1];
  const int* seq_sort = (const int*)d_in[3];
  const int* keep_cols = (const int*)d_in[4];
  const int* emb_alloc = (const int*)d_in[5];
  const int* starts = (const int*)d_in[6];
  const int* ends = (const int*)d_in[7];
  const float* w_k = (const float*)d_in[9];
  const float* w_v = (const float*)d_in[10];
  const float* w_up = (const float*)d_in[11];
  const float* w_mix = (const float*)d_in[12];
  const float* w_nin = (const float*)d_in[13];
  const float* w_nout = (const float*)d_in[14];

  char* p = (char*)d_ws;
  auto take = [&](size_t b) {
    void* r = (void*)p;
    p += (b + 255) & ~(size_t)255;
    return r;
  };
  __bf16* Aperm = (__bf16*)take((size_t)BT * Hh * 2);
  __bf16* inb = (__bf16*)take((size_t)BT * Hh * 2);
  __bf16* comb = (__bf16*)take((size_t)BT * D_EMB * 2);
  __bf16* up = (__bf16*)take((size_t)BT * D_UP * 2);
  __bf16* Ks = (__bf16*)take((size_t)MmP * Hh * 2);
  __bf16* VT = (__bf16*)take((size_t)D_EMB * MmP * 2);
  __bf16* wupB = (__bf16*)take((size_t)D_UP * D_EMB * 2);
  __bf16* wmixB = (__bf16*)take((size_t)Hh * (D_UP + Hh) * 2);
  int* la = (int*)take(Mm * 4);
  int* stA = (int*)take(NB * 4);
  int* enA = (int*)take(NB * 4);
  int* goff = (int*)take((KL + 1) * 4);
  int* gk = (int*)take(Mm * 4);
  int* ridx = (int*)take(Mm * 4);
  int* loA = (int*)take(NB * KL * 4);
  int* hiA = (int*)take(NB * KL * 4);
  int* qidx = (int*)take(BT * 4);
  int* qoffA = (int*)take(NB * KL * 4);
  int* qcntA = (int*)take(NB * KL * 4);

  // prep
  conv_bf16_kernel<<<(D_UP * D_EMB / 4 + 255) / 256, 256, 0, stream>>>(w_up, wupB, D_UP * D_EMB / 4);
  conv_bf16_kernel<<<(Hh * (D_UP + Hh) / 4 + 255) / 256, 256, 0, stream>>>(w_mix, wmixB,
                                                                           Hh * (D_UP + Hh) / 4);
  la_kernel<<<Mm / 256, 256, 0, stream>>>(keep_cols, emb_alloc, la, Mm);
  range_kernel<<<NB, 256, 0, stream>>>(starts, ends, stA, enA);
  hist_kernel<<<1, 256, 0, stream>>>(la, goff);
  place_kernel<<<KL, 256, 0, stream>>>(la, keep_cols, goff, gk, ridx);
  lohi_kernel<<<(NB * KL + 255) / 256, 256, 0, stream>>>(gk, goff, stA, enA, loA, hiA);
  gather_bf16_kernel<<<Mm, 256, 0, stream>>>(w_k, ridx, Ks, Hh / 4);
  vt_kernel<<<dim3(Mm / 64, D_EMB / 64), 256, 0, stream>>>(w_v, ridx, VT);
  qsort_kernel<<<NB, 256, 0, stream>>>(seq_sort, qidx, qoffA, qcntA);

  // pipeline
  rms_in_kernel<<<BT / 4, 256, 0, stream>>>(input, fw, w_nin, Aperm, inb);
  attn3_kernel<<<NB * KL, 256, 0, stream>>>(Aperm, Ks, VT, qidx, qoffA, qcntA, loA, hiA, fw, comb);
  gemm_bt<true><<<dim3(D_UP / 128, BT / 128), 256, 0, stream>>>(comb, D_EMB, (const __bf16*)nullptr,
                                                                0, wupB, (void*)up, BT, D_UP);
  rms_up_kernel<<<BT / 4, 256, 0, stream>>>(up, w_nout);
  gemm_bt<false><<<dim3(Hh / 128, BT / 128), 256, 0, stream>>>(up, D_UP, inb, Hh, wmixB, d_out, BT,
                                                               Hh);
}

// Round 4
// 332.852 us; speedup vs baseline: 1.4891x; 1.0960x over previous
//
#include <hip/hip_runtime.h>
#include <hip/hip_bf16.h>
#include <cstdint>
#include <cstddef>

// ---- constants (fixed by the reference problem) ----
#define Hh 1024
#define D_EMB 512
#define D_UP 2048
#define BT 16384      // B*T
#define BB_ 512
#define Mm 4096
#define MmP 4160      // Mm + 64 pad rows/cols for chunk-tail overreads
#define NB 32         // BT/BB
#define KL 64         // K_LABELS
#define NXCD 8

typedef __attribute__((ext_vector_type(4))) float f4;
typedef __attribute__((ext_vector_type(4))) __bf16 bf4;
typedef __attribute__((ext_vector_type(8))) __bf16 bf8;
typedef __attribute__((ext_vector_type(4))) float f32x4;

// ---------------- helpers ----------------
__device__ __forceinline__ void gl_lds16(const void* g, void* l) {
  __builtin_amdgcn_global_load_lds((__attribute__((address_space(1))) void*)g,
                                   (__attribute__((address_space(3))) void*)l, 16, 0, 0);
}

// ---------------- prep kernels ----------------
__global__ __launch_bounds__(256) void conv_bf16_kernel(const float* __restrict__ src,
                                                        __bf16* __restrict__ dst, int n4) {
  int i = blockIdx.x * 256 + threadIdx.x;
  if (i >= n4) return;
  f4 v = ((const f4*)src)[i];
  bf4 o = {(__bf16)v[0], (__bf16)v[1], (__bf16)v[2], (__bf16)v[3]};
  ((bf4*)dst)[i] = o;
}

__global__ __launch_bounds__(256) void gather_bf16_kernel(const float* __restrict__ src,
                                                          const int* __restrict__ idx,
                                                          __bf16* __restrict__ dst, int cols4) {
  int row = blockIdx.x;
  const f4* s = (const f4*)src + (size_t)idx[row] * cols4;
  bf4* d = (bf4*)dst + (size_t)row * cols4;
  for (int i = threadIdx.x; i < cols4; i += 256) {
    f4 v = s[i];
    bf4 o = {(__bf16)v[0], (__bf16)v[1], (__bf16)v[2], (__bf16)v[3]};
    d[i] = o;
  }
}

__global__ __launch_bounds__(256) void la_kernel(const int* __restrict__ keep,
                                                 const int* __restrict__ emb,
                                                 int* __restrict__ la, int m) {
  int i = blockIdx.x * 256 + threadIdx.x;
  if (i < m) la[i] = emb[keep[i]];
}

__global__ __launch_bounds__(256) void range_kernel(const int* __restrict__ starts,
                                                    const int* __restrict__ ends,
                                                    int* __restrict__ stA, int* __restrict__ enA) {
  int n = blockIdx.x;
  int t = threadIdx.x, lane = t & 63, wv = t >> 6;
  int s1 = min(starts[n * BB_ + t], starts[n * BB_ + t + 256]);
  int e1 = max(ends[n * BB_ + t], ends[n * BB_ + t + 256]);
#pragma unroll
  for (int off = 32; off; off >>= 1) {
    s1 = min(s1, __shfl_xor(s1, off));
    e1 = max(e1, __shfl_xor(e1, off));
  }
  __shared__ int ssh[4], esh[4];
  if (lane == 0) { ssh[wv] = s1; esh[wv] = e1; }
  __syncthreads();
  if (t == 0) {
    int s = ssh[0], e = esh[0];
#pragma unroll
    for (int k = 1; k < 4; ++k) { s = min(s, ssh[k]); e = max(e, esh[k]); }
    stA[n] = s; enA[n] = e;
  }
}

// histogram of labels over all Mm rows + exclusive prefix -> goff[KL+1]
__global__ __launch_bounds__(256) void hist_kernel(const int* __restrict__ la,
                                                   int* __restrict__ goff) {
  __shared__ int cnt[KL];
  int tid = threadIdx.x;
  if (tid < KL) cnt[tid] = 0;
  __syncthreads();
  for (int k = tid; k < Mm; k += 256) atomicAdd(&cnt[la[k]], 1);
  __syncthreads();
  if (tid == 0) {
    int a = 0;
    for (int s = 0; s < KL; ++s) { goff[s] = a; a += cnt[s]; }
    goff[KL] = a;
  }
}

// stable placement: global sorted-by-(label,k) order. one wg per label.
__global__ __launch_bounds__(256) void place_kernel(const int* __restrict__ la,
                                                    const int* __restrict__ keep,
                                                    const int* __restrict__ goff,
                                                    int* __restrict__ gk,
                                                    int* __restrict__ ridx) {
  int s = blockIdx.x;
  int tid = threadIdx.x, lane = tid & 63, wv = tid >> 6;
  __shared__ int wc[4];
  __shared__ int run;
  if (tid == 0) run = goff[s];
  __syncthreads();
  for (int base = 0; base < Mm; base += 256) {
    int k = base + tid;
    bool f = (la[k] == s);
    unsigned long long msk = __ballot(f);
    int myidx = __popcll(msk & ((1ull << lane) - 1ull));
    if (lane == 0) wc[wv] = __popcll(msk);
    __syncthreads();
    int woff = 0, tot = 0;
#pragma unroll
    for (int w = 0; w < 4; ++w) {
      if (w < wv) woff += wc[w];
      tot += wc[w];
    }
    int rbase = run;
    if (f) {
      int p = rbase + woff + myidx;
      gk[p] = k;
      ridx[p] = keep[k];
    }
    __syncthreads();
    if (tid == 0) run = rbase + tot;
    __syncthreads();
  }
}

// per (block,label): contiguous sorted-pos range [lo,hi)
__global__ __launch_bounds__(256) void lohi_kernel(const int* __restrict__ gk,
                                                   const int* __restrict__ goff,
                                                   const int* __restrict__ stA,
                                                   const int* __restrict__ enA,
                                                   int* __restrict__ loA, int* __restrict__ hiA) {
  int i = blockIdx.x * 256 + threadIdx.x;
  if (i >= NB * KL) return;
  int n = i / KL, s = i % KL;
  int b = goff[s], e = goff[s + 1];
  int st = stA[n], en = enA[n];
  int lo = b, hi = e;
  while (lo < hi) { int mid = (lo + hi) >> 1; if (gk[mid] < st) lo = mid + 1; else hi = mid; }
  int L = lo;
  lo = b; hi = e;
  while (lo < hi) { int mid = (lo + hi) >> 1; if (gk[mid] < en) lo = mid + 1; else hi = mid; }
  loA[i] = L;
  hiA[i] = lo;
}

// VT[d][pos] = bf16(w_v[ridx[pos]][d]) via LDS tile transpose
__global__ __launch_bounds__(256) void vt_kernel(const float* __restrict__ wv_,
                                                 const int* __restrict__ ridx,
                                                 __bf16* __restrict__ VT) {
  int pb = blockIdx.x * 64;
  int db = blockIdx.y * 64;
  __shared__ float T[64][65];
  int t = threadIdx.x;
  int dl = t & 63, g = t >> 6;
  for (int i = g * 16; i < g * 16 + 16; ++i) {
    int r = ridx[pb + i];
    T[dl][i] = wv_[(size_t)r * D_EMB + db + dl];
  }
  __syncthreads();
  int pl = t & 63;
  for (int j = g * 16; j < g * 16 + 16; ++j) {
    VT[(size_t)(db + j) * MmP + pb + pl] = (__bf16)T[j][pl];
  }
}

// counting sort of queries by label within each block of 512
__global__ __launch_bounds__(256) void qsort_kernel(const int* __restrict__ seq_sort,
                                                    int* __restrict__ qidx,
                                                    int* __restrict__ qoffA,
                                                    int* __restrict__ qcntA) {
  int n = blockIdx.x, tid = threadIdx.x;
  __shared__ int cnt[KL], pos[KL], pref[KL];
  if (tid < KL) cnt[tid] = 0;
  __syncthreads();
  int s0 = seq_sort[n * BB_ + tid];
  int s1 = seq_sort[n * BB_ + tid + 256];
  atomicAdd(&cnt[s0], 1);
  atomicAdd(&cnt[s1], 1);
  __syncthreads();
  if (tid == 0) {
    int a = 0;
    for (int s = 0; s < KL; ++s) { pref[s] = a; a += cnt[s]; }
  }
  __syncthreads();
  if (tid < KL) {
    pos[tid] = pref[tid];
    qoffA[n * KL + tid] = pref[tid];
    qcntA[n * KL + tid] = cnt[tid];
  }
  __syncthreads();
  int p0 = atomicAdd(&pos[s0], 1);
  qidx[n * BB_ + p0] = n * BB_ + tid;
  int p1 = atomicAdd(&pos[s1], 1);
  qidx[n * BB_ + p1] = n * BB_ + tid + 256;
}

// ---------------- RMSNorm of input (+bf16 copy of input) ----------------
__global__ __launch_bounds__(256) void rms_in_kernel(const float* __restrict__ input,
                                                     const int* __restrict__ fw,
                                                     const float* __restrict__ wn,
                                                     __bf16* __restrict__ Aperm,
                                                     __bf16* __restrict__ inb) {
  int wv = threadIdx.x >> 6, lane = threadIdx.x & 63;
  int j = blockIdx.x * 4 + wv;
  {
    const f4* src = (const f4*)(input + (size_t)fw[j] * Hh);
    f4 v[4];
    float ss = 0.f;
#pragma unroll
    for (int c = 0; c < 4; ++c) {
      v[c] = src[c * 64 + lane];
      ss += v[c][0] * v[c][0] + v[c][1] * v[c][1] + v[c][2] * v[c][2] + v[c][3] * v[c][3];
    }
#pragma unroll
    for (int off = 32; off; off >>= 1) ss += __shfl_xor(ss, off);
    float sc = rsqrtf(ss * (1.f / Hh) + 1e-6f);
    const f4* w4 = (const f4*)wn;
    bf4* dst = (bf4*)(Aperm + (size_t)j * Hh);
#pragma unroll
    for (int c = 0; c < 4; ++c) {
      f4 w = w4[c * 64 + lane];
      bf4 o = {(__bf16)(v[c][0] * sc * w[0]), (__bf16)(v[c][1] * sc * w[1]),
               (__bf16)(v[c][2] * sc * w[2]), (__bf16)(v[c][3] * sc * w[3])};
      dst[c * 64 + lane] = o;
    }
  }
  {
    const f4* src = (const f4*)(input + (size_t)j * Hh);
    bf4* dst = (bf4*)(inb + (size_t)j * Hh);
#pragma unroll
    for (int c = 0; c < 4; ++c) {
      f4 t = src[c * 64 + lane];
      bf4 o = {(__bf16)t[0], (__bf16)t[1], (__bf16)t[2], (__bf16)t[3]};
      dst[c * 64 + lane] = o;
    }
  }
}

// ---------------- grouped all-MFMA attention ----------------
__global__ __launch_bounds__(256) void attn3_kernel(const __bf16* __restrict__ Aperm,
                                                    const __bf16* __restrict__ Ks,
                                                    const __bf16* __restrict__ VT,
                                                    const int* __restrict__ qidx,
                                                    const int* __restrict__ qoffA,
                                                    const int* __restrict__ qcntA,
                                                    const int* __restrict__ loA,
                                                    const int* __restrict__ hiA,
                                                    const int* __restrict__ fw,
                                                    __bf16* __restrict__ comb) {
  int g = blockIdx.x;
  int qcnt = qcntA[g];
  if (qcnt == 0) return;
  int n = g >> 6;
  int qbase = n * BB_ + qoffA[g];
  int lo = loA[g], hi = hiA[g];
  if (lo >= hi) return;
  int tid = threadIdx.x, lane = tid & 63, wv = tid >> 6;
  int c = lane & 15, rg = lane >> 4;
  __shared__ float Sbuf[16][66];
  __shared__ __align__(16) __bf16 Plds[16][72];
  __shared__ float scl[16], lrec[16];

  for (int qt = 0; qt < qcnt; qt += 16) {
    int ql = qt + c;
    int j = qidx[qbase + (ql < qcnt ? ql : 0)];
    const __bf16* arow = Aperm + (size_t)j * Hh + rg * 8;

    float m[4] = {-1e30f, -1e30f, -1e30f, -1e30f};
    float l[4] = {0.f, 0.f, 0.f, 0.f};
    f32x4 acc[8];
    f32x4 zero = {0.f, 0.f, 0.f, 0.f};
#pragma unroll
    for (int t8 = 0; t8 < 8; ++t8) acc[t8] = zero;

    for (int p0 = lo; p0 < hi; p0 += 64) {
      int kvcol = p0 + wv * 16 + c;
      const __bf16* brow = Ks + (size_t)kvcol * Hh + rg * 8;
      f32x4 sacc = zero;
#pragma unroll
      for (int ks = 0; ks < 32; ++ks) {
        bf8 af = *(const bf8*)(arow + ks * 32);
        bf8 bf_ = *(const bf8*)(brow + ks * 32);
        sacc = __builtin_amdgcn_mfma_f32_16x16x32_bf16(af, bf_, sacc, 0, 0, 0);
      }
      bool valid = kvcol < hi;
#pragma unroll
      for (int r = 0; r < 4; ++r) Sbuf[rg * 4 + r][wv * 16 + c] = valid ? sacc[r] : -1e30f;
      __syncthreads();

#pragma unroll
      for (int r = 0; r < 4; ++r) {
        int q = wv * 4 + r;
        float s = Sbuf[q][lane];
        float cm = s;
#pragma unroll
        for (int off = 32; off; off >>= 1) cm = fmaxf(cm, __shfl_xor(cm, off));
        float mn = fmaxf(m[r], cm);
        float sc = __expf(m[r] - mn);
        float pv = __expf(s - mn);
        float ssum = pv;
#pragma unroll
        for (int off = 32; off; off >>= 1) ssum += __shfl_xor(ssum, off);
        l[r] = l[r] * sc + ssum;
        m[r] = mn;
        Plds[q][lane] = (__bf16)pv;
        if (lane == 0) scl[q] = sc;
      }
      __syncthreads();

      float sf[4];
#pragma unroll
      for (int r = 0; r < 4; ++r) sf[r] = scl[rg * 4 + r];
#pragma unroll
      for (int t8 = 0; t8 < 8; ++t8)
#pragma unroll
        for (int r = 0; r < 4; ++r) acc[t8][r] *= sf[r];

      bf8 pa0 = *(const bf8*)(&Plds[c][rg * 8]);
      bf8 pa1 = *(const bf8*)(&Plds[c][32 + rg * 8]);
#pragma unroll
      for (int tt = 0; tt < 8; ++tt) {
        int d = wv * 128 + tt * 16 + c;
        const __bf16* vrow = VT + (size_t)d * MmP + p0 + rg * 8;
        bf8 b0 = *(const bf8*)(vrow);
        bf8 b1 = *(const bf8*)(vrow + 32);
        acc[tt] = __builtin_amdgcn_mfma_f32_16x16x32_bf16(pa0, b0, acc[tt], 0, 0, 0);
        acc[tt] = __builtin_amdgcn_mfma_f32_16x16x32_bf16(pa1, b1, acc[tt], 0, 0, 0);
      }
      __syncthreads();
    }

    if (lane == 0) {
#pragma unroll
      for (int r = 0; r < 4; ++r) lrec[wv * 4 + r] = l[r];
    }
    __syncthreads();
    float inv[4];
    size_t obase[4];
    bool oval[4];
#pragma unroll
    for (int r = 0; r < 4; ++r) {
      int qq = qt + rg * 4 + r;
      oval[r] = qq < qcnt;
      int j2 = qidx[qbase + (oval[r] ? qq : 0)];
      obase[r] = (size_t)fw[j2] * D_EMB;
      float lv = lrec[rg * 4 + r];
      inv[r] = 1.f / lv;
    }
#pragma unroll
    for (int tt = 0; tt < 8; ++tt) {
      int d = wv * 128 + tt * 16 + c;
#pragma unroll
      for (int r = 0; r < 4; ++r) {
        if (oval[r]) comb[obase[r] + d] = (__bf16)(acc[tt][r] * inv[r]);
      }
    }
    __syncthreads();
  }
}

// ---------------- 256x256 phase-pipelined GEMM: C = X @ W^T ----------------
// BK=32, 4-buffer LDS ring, counted vmcnt(8), T2 XOR-swizzle, T5 setprio,
// T1 XCD-chunked block swizzle. 8 waves (2Mx4N), per-wave C = 128x64.
// X split in two K-segments (x0: k0 cols, x1: k1 cols); W is [N][K] full.
template <bool OUT_BF16>
__global__ __launch_bounds__(512, 2) void gemm8p(const __bf16* __restrict__ x0, int k0,
                                                 const __bf16* __restrict__ x1, int k1,
                                                 const __bf16* __restrict__ w,
                                                 void* __restrict__ outp, int Mt, int Nt) {
  __shared__ __align__(16) __bf16 lds[4][2][256 * 32];  // [buf][A/B][row*32+col]
  const int nwg = Mt * Nt;
  const int bid = blockIdx.x;
  const int swz = (bid % NXCD) * (nwg / NXCD) + bid / NXCD;
  const int m0 = (swz / Nt) * 256, n0 = (swz % Nt) * 256;
  const int K = k0 + k1;
  const int NT = K >> 5;
  const int N = Nt * 256;
  const int tid = threadIdx.x, lane = tid & 63, wvi = tid >> 6;
  const int wr = wvi >> 2, wc = wvi & 3;

  // staging geometry: per issue j (0/1): row = j*128 + tid/4, phys col byte = (tid&3)*16
  const int srow = tid >> 2;
  const int spb = (tid & 3) * 16;

  // frag ds_read offset (bytes, relative to row0*64): swizzle byte ^= ((row>>1)&3)<<4
  const int c = lane & 15, rg = lane >> 4;
  const int fa_off = c * 64 + ((rg ^ ((c >> 1) & 3)) << 4);

  auto stage_half = [&](int t, int j) {
    int kg = t * 32;
    const __bf16* xs;
    int ld, kk;
    if (kg < k0) { xs = x0; ld = k0; kk = kg; }
    else         { xs = x1; ld = k1; kk = kg - k0; }
    int b = t & 3;
    int r = j * 128 + srow;
    int lcol = (spb ^ (((r >> 1) & 3) << 4)) >> 1;  // logical col (elements)
    // A
    gl_lds16(xs + (size_t)(m0 + r) * ld + kk + lcol,
             (void*)((char*)&lds[b][0][0] + r * 64 + spb));
    // B
    gl_lds16(w + (size_t)(n0 + r) * K + kg + lcol,
             (void*)((char*)&lds[b][1][0] + r * 64 + spb));
  };

  f32x4 acc[8][4];
  f32x4 zero = {0.f, 0.f, 0.f, 0.f};
#pragma unroll
  for (int a = 0; a < 8; ++a)
#pragma unroll
    for (int bnx = 0; bnx < 4; ++bnx) acc[a][bnx] = zero;

  // prologue: stage tiles 0,1,2 (12 wave-loads); wait until tile0 landed (<=8 left)
#pragma unroll
  for (int t = 0; t < 3; ++t) {
    stage_half(t, 0);
    stage_half(t, 1);
  }
  asm volatile("s_waitcnt vmcnt(8)" ::: "memory");
  __builtin_amdgcn_s_barrier();

  for (int t = 0; t < NT; ++t) {
    const char* Abase = (const char*)&lds[t & 3][0][0];
    const char* Bbase = (const char*)&lds[t & 3][1][0];
    bf8 bfr[4];
#pragma unroll
    for (int ri = 0; ri < 2; ++ri) {
      // issue half of tile t+3's staging (2 gl_lds per wave)
      if (t + 3 < NT) stage_half(t + 3, ri);
      // ds_read this phase's frags
      bf8 afr[4];
#pragma unroll
      for (int fi = 0; fi < 4; ++fi)
        afr[fi] = *(const bf8*)(Abase + (wr * 128 + ri * 64 + fi * 16) * 64 + fa_off);
      if (ri == 0) {
#pragma unroll
        for (int fi = 0; fi < 4; ++fi)
          bfr[fi] = *(const bf8*)(Bbase + (wc * 64 + fi * 16) * 64 + fa_off);
      }
      __builtin_amdgcn_s_barrier();
      __builtin_amdgcn_s_setprio(1);
#pragma unroll
      for (int fi = 0; fi < 4; ++fi)
#pragma unroll
        for (int ni = 0; ni < 4; ++ni)
          acc[ri * 4 + fi][ni] =
              __builtin_amdgcn_mfma_f32_16x16x32_bf16(afr[fi], bfr[ni], acc[ri * 4 + fi][ni], 0, 0, 0);
      __builtin_amdgcn_s_setprio(0);
      if (ri == 1) asm volatile("s_waitcnt vmcnt(8)" ::: "memory");
      __builtin_amdgcn_s_barrier();
    }
  }

  // epilogue
  const int r0 = (lane >> 4) * 4, cc = lane & 15;
#pragma unroll
  for (int mi = 0; mi < 8; ++mi) {
    int rowb = m0 + wr * 128 + (mi >> 2) * 64 + (mi & 3) * 16 + r0;
#pragma unroll
    for (int ni = 0; ni < 4; ++ni) {
      int col = n0 + wc * 64 + ni * 16 + cc;
#pragma unroll
      for (int r = 0; r < 4; ++r) {
        float v = acc[mi][ni][r];
        if (OUT_BF16)
          ((__bf16*)outp)[(size_t)(rowb + r) * N + col] = (__bf16)v;
        else
          ((float*)outp)[(size_t)(rowb + r) * N + col] = v;
      }
    }
  }
}

// ---------------- in-place RMSNorm of up ----------------
__global__ __launch_bounds__(256) void rms_up_kernel(__bf16* __restrict__ up,
                                                     const float* __restrict__ wn) {
  int wv = threadIdx.x >> 6, lane = threadIdx.x & 63;
  size_t j = (size_t)blockIdx.x * 4 + wv;
  bf8* row = (bf8*)(up + j * D_UP);
  bf8 v[4];
  float ss = 0.f;
#pragma unroll
  for (int c = 0; c < 4; ++c) {
    v[c] = row[c * 64 + lane];
#pragma unroll
    for (int i = 0; i < 8; ++i) { float f = (float)v[c][i]; ss += f * f; }
  }
#pragma unroll
  for (int off = 32; off; off >>= 1) ss += __shfl_xor(ss, off);
  float sc = rsqrtf(ss * (1.f / D_UP) + 1e-6f);
#pragma unroll
  for (int c = 0; c < 4; ++c) {
    int ebase = (c * 64 + lane) * 8;
    f4 wa = *(const f4*)(wn + ebase);
    f4 wb = *(const f4*)(wn + ebase + 4);
    bf8 o;
#pragma unroll
    for (int i = 0; i < 4; ++i) o[i] = (__bf16)((float)v[c][i] * sc * wa[i]);
#pragma unroll
    for (int i = 0; i < 4; ++i) o[4 + i] = (__bf16)((float)v[c][4 + i] * sc * wb[i]);
    row[c * 64 + lane] = o;
  }
}

// ---------------- launch ----------------
extern "C" void kernel_launch(void* const* d_in, const int* in_sizes, int n_in, void* d_out,
                              int out_size, void* d_ws, size_t ws_size, hipStream_t stream) {
  const float* input = (const float*)d_in[0];
  const int* fw = (const int*)d_in[1];
  const int* seq_sort = (const int*)d_in[3];
  const int* keep_cols = (const int*)d_in[4];
  const int* emb_alloc = (const int*)d_in[5];
  const int* starts = (const int*)d_in[6];
  const int* ends = (const int*)d_in[7];
  const float* w_k = (const float*)d_in[9];
  const float* w_v = (const float*)d_in[10];
  const float* w_up = (const float*)d_in[11];
  const float* w_mix = (const float*)d_in[12];
  const float* w_nin = (const float*)d_in[13];
  const float* w_nout = (const float*)d_in[14];

  char* p = (char*)d_ws;
  auto take = [&](size_t b) {
    void* r = (void*)p;
    p += (b + 255) & ~(size_t)255;
    return r;
  };
  __bf16* Aperm = (__bf16*)take((size_t)BT * Hh * 2);
  __bf16* inb = (__bf16*)take((size_t)BT * Hh * 2);
  __bf16* comb = (__bf16*)take((size_t)BT * D_EMB * 2);
  __bf16* up = (__bf16*)take((size_t)BT * D_UP * 2);
  __bf16* Ks = (__bf16*)take((size_t)MmP * Hh * 2);
  __bf16* VT = (__bf16*)take((size_t)D_EMB * MmP * 2);
  __bf16* wupB = (__bf16*)take((size_t)D_UP * D_EMB * 2);
  __bf16* wmixB = (__bf16*)take((size_t)Hh * (D_UP + Hh) * 2);
  int* la = (int*)take(Mm * 4);
  int* stA = (int*)take(NB * 4);
  int* enA = (int*)take(NB * 4);
  int* goff = (int*)take((KL + 1) * 4);
  int* gk = (int*)take(Mm * 4);
  int* ridx = (int*)take(Mm * 4);
  int* loA = (int*)take(NB * KL * 4);
  int* hiA = (int*)take(NB * KL * 4);
  int* qidx = (int*)take(BT * 4);
  int* qoffA = (int*)take(NB * KL * 4);
  int* qcntA = (int*)take(NB * KL * 4);

  // prep
  conv_bf16_kernel<<<(D_UP * D_EMB / 4 + 255) / 256, 256, 0, stream>>>(w_up, wupB, D_UP * D_EMB / 4);
  conv_bf16_kernel<<<(Hh * (D_UP + Hh) / 4 + 255) / 256, 256, 0, stream>>>(w_mix, wmixB,
                                                                           Hh * (D_UP + Hh) / 4);
  la_kernel<<<Mm / 256, 256, 0, stream>>>(keep_cols, emb_alloc, la, Mm);
  range_kernel<<<NB, 256, 0, stream>>>(starts, ends, stA, enA);
  hist_kernel<<<1, 256, 0, stream>>>(la, goff);
  place_kernel<<<KL, 256, 0, stream>>>(la, keep_cols, goff, gk, ridx);
  lohi_kernel<<<(NB * KL + 255) / 256, 256, 0, stream>>>(gk, goff, stA, enA, loA, hiA);
  gather_bf16_kernel<<<Mm, 256, 0, stream>>>(w_k, ridx, Ks, Hh / 4);
  vt_kernel<<<dim3(Mm / 64, D_EMB / 64), 256, 0, stream>>>(w_v, ridx, VT);
  qsort_kernel<<<NB, 256, 0, stream>>>(seq_sort, qidx, qoffA, qcntA);

  // pipeline
  rms_in_kernel<<<BT / 4, 256, 0, stream>>>(input, fw, w_nin, Aperm, inb);
  attn3_kernel<<<NB * KL, 256, 0, stream>>>(Aperm, Ks, VT, qidx, qoffA, qcntA, loA, hiA, fw, comb);
  gemm8p<true><<<BT / 256 * (D_UP / 256), 512, 0, stream>>>(comb, D_EMB, (const __bf16*)nullptr, 0,
                                                            wupB, (void*)up, BT / 256, D_UP / 256);
  rms_up_kernel<<<BT / 4, 256, 0, stream>>>(up, w_nout);
  gemm8p<false><<<BT / 256 * (Hh / 256), 512, 0, stream>>>(up, D_UP, inb, Hh, wmixB, d_out,
                                                           BT / 256, Hh / 256);
}